// Round 1
// baseline (17521.227 us; speedup 1.0000x reference)
//
#include <hip/hip_runtime.h>

// ---------------------------------------------------------------------------
// MetaRNN (HyperNetwork-conditioned RNN), MI355X gfx950.
// Strategy:
//   per layer:
//     1) GEMM (MFMA, split-bf16 x3): xW = x @ Wih^T  [B,T,H]
//                                    xH = x @ Wih_hy[:, :D]^T [B,T,HH]
//     2) scan kernel: 16 workgroups x 16 batch rows, 512 sequential steps,
//        all recurrent matmuls as 16x16x32 bf16 MFMA with split-bf16 3-term
//        products (fp32-grade accuracy). Weights pre-split/fragmented by a
//        prep kernel; activations live as A-fragments in LDS.
// ws layout: [xW f32 134MB][xH f32 67MB][weight frags ~2MB]  (needs ~194MB)
// ---------------------------------------------------------------------------

#define DEVI __device__ __forceinline__

typedef __bf16 bf16x8 __attribute__((ext_vector_type(8)));
typedef float f32x4 __attribute__((ext_vector_type(4)));
typedef unsigned short u16;
typedef unsigned int u32;
typedef u32 u32x4 __attribute__((ext_vector_type(4)));
typedef u16 u16x8 __attribute__((ext_vector_type(8)));

constexpr int B_ = 256, T_ = 512, D_ = 256, H_ = 256, HH_ = 128, E_ = 32;
constexpr int BT = B_ * T_;

// fragment-buffer offsets (u16 elements), per layer
constexpr int OXW = 0,      PXW = 16 * 8 * 512;   // Wih      [16nt][8kt]
constexpr int OXH = 131072, PXH = 8 * 8 * 512;    // Wih_hy_x [8nt][8kt]
constexpr int OHY = 196608, PHY = 8 * 12 * 512;   // [U_hy|Whh_hy] [8nt][12kt]
constexpr int OWHH = 294912, PWHH = 16 * 8 * 512; // Whh      [16nt][8kt]
constexpr int OWHZ = 425984, PWHZ = 6 * 4 * 512;  // Whz flat [6nt][4kt]
constexpr int OWZD = 450560, PWZD = 48 * 512;     // Wzd      [3g][16nt][1kt]
constexpr int LSTRIDE = 499712;                   // u16 per layer

constexpr size_t WS_XW = 0;
constexpr size_t WS_XH = (size_t)BT * H_ * 4;
constexpr size_t WS_FR = WS_XH + (size_t)BT * HH_ * 4;

DEVI u16 f2bf(float v) {            // round-to-nearest-even fp32 -> bf16 bits
  u32 u = __float_as_uint(v);
  u += 0x7fffu + ((u >> 16) & 1u);
  return (u16)(u >> 16);
}
DEVI float bf2f(u16 s) { return __uint_as_float(((u32)s) << 16); }
DEVI void split2(float v, u16 &hi, u16 &lo) {
  hi = f2bf(v);
  lo = f2bf(v - bf2f(hi));          // Sterbenz: subtraction exact
}
DEVI bf16x8 ldfrag(const u16 *p) {
  u32x4 v = *reinterpret_cast<const u32x4 *>(p);
  return __builtin_bit_cast(bf16x8, v);
}
DEVI f32x4 mfma3(bf16x8 ah, bf16x8 al, bf16x8 bh, bf16x8 bl, f32x4 c) {
  c = __builtin_amdgcn_mfma_f32_16x16x32_bf16(ah, bh, c, 0, 0, 0);
  c = __builtin_amdgcn_mfma_f32_16x16x32_bf16(ah, bl, c, 0, 0, 0);
  c = __builtin_amdgcn_mfma_f32_16x16x32_bf16(al, bh, c, 0, 0, 0);
  return c;
}
DEVI float tanh_fast(float x) {
  float e = __expf(2.0f * x);       // inf-safe: ->1 / ->-1 at extremes
  return 1.0f - 2.0f / (e + 1.0f);
}

// ---------------------------------------------------------------------------
// prep: split all weights to bf16 hi/lo and lay out as 16x16x32 B-fragments.
// entry = (matrix, nt, kt); 488 entries/layer; thread = (entry, lane).
// fragment: element j, lane l  <-  W[nt*16 + (l&15), kt*32 + (l>>4)*8 + j]
// ---------------------------------------------------------------------------
__global__ void metarnn_prep(const float *__restrict__ Wih,
                             const float *__restrict__ Whh,
                             const float *__restrict__ Wih_hy,
                             const float *__restrict__ Whh_hy,
                             const float *__restrict__ Whz,
                             const float *__restrict__ Wzd,
                             u16 *__restrict__ fr) {
  int gid = blockIdx.x * 256 + threadIdx.x;
  int lane = gid & 63;
  int e = gid >> 6;
  if (e >= 2 * 488) return;
  int l = e / 488, r = e - l * 488;
  u16 *base = fr + (size_t)l * LSTRIDE;
  int rowL = lane & 15, kg = (lane >> 4) << 3;

  const float *src = nullptr;
  int ld = 0, nt = 0, kt = 0, KT = 1, special = 0;
  u16 *dh = nullptr, *dl = nullptr;
  if (r < 128) {            // Wih [H,D]
    nt = r >> 3; kt = r & 7; KT = 8;
    src = Wih + (size_t)l * H_ * D_; ld = D_;
    dh = base + OXW; dl = dh + PXW;
  } else if (r < 192) {     // Wih_hy x-part [HH, 0:256]
    r -= 128; nt = r >> 3; kt = r & 7; KT = 8;
    src = Wih_hy + (size_t)l * HH_ * (D_ + H_); ld = D_ + H_;
    dh = base + OXH; dl = dh + PXH;
  } else if (r < 288) {     // concat [U_hy | Whh_hy]  [HH, 384]
    r -= 192; nt = r / 12; kt = r - nt * 12; KT = 12; special = 1;
    dh = base + OHY; dl = dh + PHY;
  } else if (r < 416) {     // Whh [H,H]
    r -= 288; nt = r >> 3; kt = r & 7; KT = 8;
    src = Whh + (size_t)l * H_ * H_; ld = H_;
    dh = base + OWHH; dl = dh + PWHH;
  } else if (r < 440) {     // Whz flat [96, HH]
    r -= 416; nt = r >> 2; kt = r & 3; KT = 4;
    src = Whz + (size_t)l * 3 * E_ * HH_; ld = HH_;
    dh = base + OWHZ; dl = dh + PWHZ;
  } else {                  // Wzd per g: [H, E]
    r -= 440; int g = r >> 4; nt = r & 15; kt = 0; KT = 1;
    src = Wzd + (size_t)(l * 3 + g) * H_ * E_; ld = E_;
    dh = base + OWZD + g * 16 * 512; dl = base + OWZD + PWZD + g * 16 * 512;
  }
  int row = nt * 16 + rowL;
  long dof = ((long)(nt * KT + kt) * 64 + lane) * 8;
  for (int j = 0; j < 8; ++j) {
    int k = kt * 32 + kg + j;
    float v;
    if (special) {
      v = (k < 256) ? Wih_hy[((size_t)l * HH_ + row) * (D_ + H_) + 256 + k]
                    : Whh_hy[((size_t)l * HH_ + row) * HH_ + (k - 256)];
    } else {
      v = src[(size_t)row * ld + k];
    }
    u16 hi, lo;
    split2(v, hi, lo);
    dh[dof + j] = hi;
    dl[dof + j] = lo;
  }
}

// ---------------------------------------------------------------------------
// GEMM: xW[m, 0:256] , xH[m, 0:128]  =  x[m, 0:256] @ {Wih, Wih_hy_x}^T
// grid: BT/32 blocks of 256 threads; wave w owns col-tiles [6w, 6w+6),
// both 16-row M-subtiles. Split-bf16 x3 products.
// ---------------------------------------------------------------------------
__global__ __launch_bounds__(256, 1) void metarnn_gemm(
    const float *__restrict__ x, const u16 *__restrict__ fr,
    float *__restrict__ xW, float *__restrict__ xH) {
  int w = threadIdx.x >> 6, lane = threadIdx.x & 63;
  int m0 = blockIdx.x * 32;
  int rowL = lane & 15, kg = (lane >> 4) << 3;
  f32x4 acc[2][6] = {};
  const u16 *fxw_h = fr + OXW, *fxw_l = fxw_h + PXW;
  const u16 *fxh_h = fr + OXH, *fxh_l = fxh_h + PXH;

  for (int kt = 0; kt < 8; ++kt) {
    bf16x8 ah[2], al[2];
    for (int s = 0; s < 2; ++s) {
      const float *xp = x + (size_t)(m0 + s * 16 + rowL) * 256 + kt * 32 + kg;
      u16x8 vh, vl;
#pragma unroll
      for (int j = 0; j < 8; ++j) {
        u16 hi, lo;
        split2(xp[j], hi, lo);
        vh[j] = hi; vl[j] = lo;
      }
      ah[s] = __builtin_bit_cast(bf16x8, vh);
      al[s] = __builtin_bit_cast(bf16x8, vl);
    }
#pragma unroll
    for (int q = 0; q < 6; ++q) {
      int nt = w * 6 + q;
      long o = (nt < 16) ? ((long)(nt * 8 + kt) * 64 + lane) * 8
                         : ((long)((nt - 16) * 8 + kt) * 64 + lane) * 8;
      const u16 *bh = (nt < 16) ? fxw_h + o : fxh_h + o;
      const u16 *bl = (nt < 16) ? fxw_l + o : fxh_l + o;
      bf16x8 B0 = ldfrag(bh), B1 = ldfrag(bl);
      acc[0][q] = mfma3(ah[0], al[0], B0, B1, acc[0][q]);
      acc[1][q] = mfma3(ah[1], al[1], B0, B1, acc[1][q]);
    }
  }
  for (int s = 0; s < 2; ++s)
    for (int q = 0; q < 6; ++q) {
      int nt = w * 6 + q;
#pragma unroll
      for (int r = 0; r < 4; ++r) {
        int row = m0 + s * 16 + (lane >> 4) * 4 + r;
        if (nt < 16)
          xW[(size_t)row * H_ + nt * 16 + rowL] = acc[s][q][r];
        else
          xH[(size_t)row * HH_ + (nt - 16) * 16 + rowL] = acc[s][q][r];
      }
    }
}

// ---------------------------------------------------------------------------
// scan: 16 blocks x 256 threads (4 waves). Block owns batch rows
// [16*blockIdx, +16). Per step:
//  P1: preA[16,128] = hcat @ [U_hy|Whh_hy]^T ; hWhh[16,256] = h @ Whh^T
//  P2: hh_new = tanh(preA + xH_t + b_hy) -> split frags into hcat[8..11]
//  P3/P4: z = hh_new @ Whz^T + bz -> split frags
//  P5: d[g] = z_g @ Wzd_g^T
//  P6: h_new = tanh(d0*xW_t + d1*hWhh + d2 + b) -> y, split frags hcat[0..7]
// ---------------------------------------------------------------------------
__global__ __launch_bounds__(256, 1) void metarnn_scan(
    const float *__restrict__ xW, const float *__restrict__ xH,
    const u16 *__restrict__ fr, const float *__restrict__ bmain,
    const float *__restrict__ bhy, const float *__restrict__ bz,
    float *__restrict__ y, float *__restrict__ hlast, int layer, int isLast) {
  __shared__ __align__(16) u16 hc_h[12 * 512];
  __shared__ __align__(16) u16 hc_l[12 * 512];
  __shared__ __align__(16) u16 zf_h[3 * 512];
  __shared__ __align__(16) u16 zf_l[3 * 512];

  int tid = threadIdx.x, w = tid >> 6, lane = tid & 63;
  int bs = blockIdx.x * 16;
  int rowL = lane & 15, r0 = (lane >> 4) * 4;

  for (int i = tid; i < 12 * 512; i += 256) { hc_h[i] = 0; hc_l[i] = 0; }
  for (int i = tid; i < 3 * 512; i += 256) { zf_h[i] = 0; zf_l[i] = 0; }
  __syncthreads();

  const u16 *FHY = fr + OHY, *FHYl = FHY + PHY;
  const u16 *FWH = fr + OWHH, *FWHl = FWH + PWHH;
  const u16 *FWZ = fr + OWHZ, *FWZl = FWZ + PWHZ;
  const u16 *FZD = fr + OWZD, *FZDl = FZD + PWZD;
  const float *bh_p = bhy + layer * HH_;
  const float *bz_p = bz + layer * 3 * E_;
  const float *bm_p = bmain + layer * H_;

  for (int t = 0; t < T_; ++t) {
    // ---- P1: preA (2 tiles) + hWhh (4 tiles) -------------------------------
    f32x4 aA[2] = {};
    f32x4 aW[4] = {};
    for (int kt = 0; kt < 12; ++kt) {
      bf16x8 ah = ldfrag(&hc_h[kt * 512 + lane * 8]);
      bf16x8 al = ldfrag(&hc_l[kt * 512 + lane * 8]);
#pragma unroll
      for (int p = 0; p < 2; ++p) {
        int nt = 2 * w + p;
        long o = ((long)(nt * 12 + kt) * 64 + lane) * 8;
        aA[p] = mfma3(ah, al, ldfrag(FHY + o), ldfrag(FHYl + o), aA[p]);
      }
      if (kt < 8) {
#pragma unroll
        for (int q = 0; q < 4; ++q) {
          int nt = 4 * w + q;
          long o = ((long)(nt * 8 + kt) * 64 + lane) * 8;
          aW[q] = mfma3(ah, al, ldfrag(FWH + o), ldfrag(FWHl + o), aW[q]);
        }
      }
    }
    __syncthreads();

    // ---- P2: hh_new --------------------------------------------------------
    for (int p = 0; p < 2; ++p) {
      int c = (2 * w + p) * 16 + rowL;     // 0..127
      float bhv = bh_p[c];
#pragma unroll
      for (int r = 0; r < 4; ++r) {
        int m = r0 + r;
        float xh = xH[((size_t)(bs + m) * T_ + t) * HH_ + c];
        float v = tanh_fast(aA[p][r] + xh + bhv);
        u16 hi, lo;
        split2(v, hi, lo);
        int k = 256 + c;
        int di = (k >> 5) * 512 + (m + (((k & 31) >> 3) << 4)) * 8 + (k & 7);
        hc_h[di] = hi;
        hc_l[di] = lo;
      }
    }
    __syncthreads();

    // ---- P3: z MFMAs -------------------------------------------------------
    f32x4 aZ[2] = {};
    int nz = (w < 2) ? 2 : 1;
    for (int zi = 0; zi < nz; ++zi) {
      int nt = (zi == 0) ? w : (4 + w);
      for (int kt = 0; kt < 4; ++kt) {
        bf16x8 ah = ldfrag(&hc_h[(8 + kt) * 512 + lane * 8]);
        bf16x8 al = ldfrag(&hc_l[(8 + kt) * 512 + lane * 8]);
        long o = ((long)(nt * 4 + kt) * 64 + lane) * 8;
        aZ[zi] = mfma3(ah, al, ldfrag(FWZ + o), ldfrag(FWZl + o), aZ[zi]);
      }
    }
    // ---- P4: z += bz, split to frags --------------------------------------
    for (int zi = 0; zi < nz; ++zi) {
      int nt = (zi == 0) ? w : (4 + w);
      int c = nt * 16 + rowL;              // 0..95
      float bzv = bz_p[c];
      int g = c >> 5, eidx = c & 31;
#pragma unroll
      for (int r = 0; r < 4; ++r) {
        int m = r0 + r;
        float v = aZ[zi][r] + bzv;
        u16 hi, lo;
        split2(v, hi, lo);
        int di = g * 512 + (m + ((eidx >> 3) << 4)) * 8 + (eidx & 7);
        zf_h[di] = hi;
        zf_l[di] = lo;
      }
    }
    __syncthreads();

    // ---- P5: d = z @ Wzd^T (per g) ----------------------------------------
    f32x4 aD[3][4];
#pragma unroll
    for (int g = 0; g < 3; ++g) {
      bf16x8 zh = ldfrag(&zf_h[g * 512 + lane * 8]);
      bf16x8 zl = ldfrag(&zf_l[g * 512 + lane * 8]);
#pragma unroll
      for (int q = 0; q < 4; ++q) {
        int nt = 4 * w + q;
        long o = ((long)(g * 16 + nt) * 64 + lane) * 8;
        f32x4 zero = {};
        aD[g][q] = mfma3(zh, zl, ldfrag(FZD + o), ldfrag(FZDl + o), zero);
      }
    }
    // ---- P6: h_new, write y, refresh h frags ------------------------------
    for (int q = 0; q < 4; ++q) {
      int c = 64 * w + q * 16 + rowL;      // 0..255
      float bbv = bm_p[c];
#pragma unroll
      for (int r = 0; r < 4; ++r) {
        int m = r0 + r;
        size_t gi = (size_t)(bs + m) * T_ + t;
        float xw = xW[gi * H_ + c];
        float arg = aD[0][q][r] * xw + aD[1][q][r] * aW[q][r] + aD[2][q][r] + bbv;
        float h = tanh_fast(arg);
        y[gi * H_ + c] = h;
        if (isLast && t == T_ - 1) hlast[(size_t)(bs + m) * H_ + c] = h;
        u16 hi, lo;
        split2(h, hi, lo);
        int di = (c >> 5) * 512 + (m + (((c & 31) >> 3) << 4)) * 8 + (c & 7);
        hc_h[di] = hi;
        hc_l[di] = lo;
      }
    }
    __syncthreads();
  }
}

// ---------------------------------------------------------------------------
extern "C" void kernel_launch(void *const *d_in, const int *in_sizes, int n_in,
                              void *d_out, int out_size, void *d_ws,
                              size_t ws_size, hipStream_t stream) {
  (void)in_sizes; (void)n_in; (void)out_size; (void)ws_size;
  const float *input  = (const float *)d_in[0];
  const float *Wih    = (const float *)d_in[1];
  const float *Whh    = (const float *)d_in[2];
  const float *b      = (const float *)d_in[3];
  const float *Wih_hy = (const float *)d_in[4];
  const float *Whh_hy = (const float *)d_in[5];
  const float *b_hy   = (const float *)d_in[6];
  const float *Whz    = (const float *)d_in[7];
  const float *bz     = (const float *)d_in[8];
  const float *Wzd    = (const float *)d_in[9];

  float *out = (float *)d_out;
  float *xW = (float *)((char *)d_ws + WS_XW);
  float *xH = (float *)((char *)d_ws + WS_XH);
  u16 *fr = (u16 *)((char *)d_ws + WS_FR);
  float *hlast = out + (size_t)BT * H_;

  metarnn_prep<<<dim3(244), dim3(256), 0, stream>>>(Wih, Whh, Wih_hy, Whh_hy,
                                                    Whz, Wzd, fr);
  for (int l = 0; l < 2; ++l) {
    const float *xsrc = (l == 0) ? input : out;   // layer1 reads layer0 output
    const u16 *frl = fr + (size_t)l * LSTRIDE;
    metarnn_gemm<<<dim3(BT / 32), dim3(256), 0, stream>>>(xsrc, frl, xW, xH);
    metarnn_scan<<<dim3(16), dim3(256), 0, stream>>>(
        xW, xH, frl, b, b_hy, bz, out, hlast, l, (l == 1) ? 1 : 0);
  }
}

// Round 2
// 11903.816 us; speedup vs baseline: 1.4719x; 1.4719x over previous
//
#include <hip/hip_runtime.h>

// ---------------------------------------------------------------------------
// MetaRNN (HyperNetwork-conditioned RNN), MI355X gfx950.  v2
//   per layer:
//     1) GEMM (MFMA, split-bf16 x3): xW = x @ Wih^T, xH = x @ Wih_hy_x^T
//     2) scan: 16 blocks x 512 thr (8 waves, 2/SIMD). Weights: z/d register-
//        resident; Whh/HY streamed from L2 through a 3-deep rotating register
//        pipeline (t-invariant addresses). Activations as MFMA A-fragments in
//        30 KB LDS. Split-bf16 3-term products (fp32-grade, same numerics as
//        v1: absmax 0.0039 validated).
// ---------------------------------------------------------------------------

#define DEVI __device__ __forceinline__

typedef __bf16 bf16x8 __attribute__((ext_vector_type(8)));
typedef float f32x4 __attribute__((ext_vector_type(4)));
typedef unsigned short u16;
typedef unsigned int u32;
typedef u32 u32x4 __attribute__((ext_vector_type(4)));
typedef u16 u16x8 __attribute__((ext_vector_type(8)));

constexpr int B_ = 256, T_ = 512, D_ = 256, H_ = 256, HH_ = 128, E_ = 32;
constexpr int BT = B_ * T_;

// fragment-buffer offsets (u16 elements), per layer
constexpr int OXW = 0,      PXW = 16 * 8 * 512;   // Wih      [16nt][8kt]
constexpr int OXH = 131072, PXH = 8 * 8 * 512;    // Wih_hy_x [8nt][8kt]
constexpr int OHY = 196608, PHY = 8 * 12 * 512;   // [U_hy|Whh_hy] [8nt][12kt]
constexpr int OWHH = 294912, PWHH = 16 * 8 * 512; // Whh      [16nt][8kt]
constexpr int OWHZ = 425984, PWHZ = 6 * 4 * 512;  // Whz flat [6nt][4kt]
constexpr int OWZD = 450560, PWZD = 48 * 512;     // Wzd      [3g][16nt][1kt]
constexpr int LSTRIDE = 499712;                   // u16 per layer

constexpr size_t WS_XW = 0;
constexpr size_t WS_XH = (size_t)BT * H_ * 4;
constexpr size_t WS_FR = WS_XH + (size_t)BT * HH_ * 4;

DEVI u16 f2bf(float v) {            // round-to-nearest-even fp32 -> bf16 bits
  u32 u = __float_as_uint(v);
  u += 0x7fffu + ((u >> 16) & 1u);
  return (u16)(u >> 16);
}
DEVI float bf2f(u16 s) { return __uint_as_float(((u32)s) << 16); }
DEVI void split2(float v, u16 &hi, u16 &lo) {
  hi = f2bf(v);
  lo = f2bf(v - bf2f(hi));          // exact subtraction
}
DEVI bf16x8 ldfrag(const u16 *p) {
  u32x4 v = *reinterpret_cast<const u32x4 *>(p);
  return __builtin_bit_cast(bf16x8, v);
}
DEVI f32x4 mfma3(bf16x8 ah, bf16x8 al, bf16x8 bh, bf16x8 bl, f32x4 c) {
  c = __builtin_amdgcn_mfma_f32_16x16x32_bf16(ah, bh, c, 0, 0, 0);
  c = __builtin_amdgcn_mfma_f32_16x16x32_bf16(ah, bl, c, 0, 0, 0);
  c = __builtin_amdgcn_mfma_f32_16x16x32_bf16(al, bh, c, 0, 0, 0);
  return c;
}
DEVI float tanh_fast(float x) {
  float e = __expf(2.0f * x);       // inf-safe: ->1 / ->-1 at extremes
  return 1.0f - 2.0f / (e + 1.0f);
}

// ---------------------------------------------------------------------------
// prep: split all weights to bf16 hi/lo and lay out as 16x16x32 B-fragments.
// fragment: element j, lane l  <-  W[nt*16 + (l&15), kt*32 + (l>>4)*8 + j]
// ---------------------------------------------------------------------------
__global__ void metarnn_prep(const float *__restrict__ Wih,
                             const float *__restrict__ Whh,
                             const float *__restrict__ Wih_hy,
                             const float *__restrict__ Whh_hy,
                             const float *__restrict__ Whz,
                             const float *__restrict__ Wzd,
                             u16 *__restrict__ fr) {
  int gid = blockIdx.x * 256 + threadIdx.x;
  int lane = gid & 63;
  int e = gid >> 6;
  if (e >= 2 * 488) return;
  int l = e / 488, r = e - l * 488;
  u16 *base = fr + (size_t)l * LSTRIDE;
  int rowL = lane & 15, kg = (lane >> 4) << 3;

  const float *src = nullptr;
  int ld = 0, nt = 0, kt = 0, KT = 1, special = 0;
  u16 *dh = nullptr, *dl = nullptr;
  if (r < 128) {            // Wih [H,D]
    nt = r >> 3; kt = r & 7; KT = 8;
    src = Wih + (size_t)l * H_ * D_; ld = D_;
    dh = base + OXW; dl = dh + PXW;
  } else if (r < 192) {     // Wih_hy x-part [HH, 0:256]
    r -= 128; nt = r >> 3; kt = r & 7; KT = 8;
    src = Wih_hy + (size_t)l * HH_ * (D_ + H_); ld = D_ + H_;
    dh = base + OXH; dl = dh + PXH;
  } else if (r < 288) {     // concat [U_hy | Whh_hy]  [HH, 384]
    r -= 192; nt = r / 12; kt = r - nt * 12; KT = 12; special = 1;
    dh = base + OHY; dl = dh + PHY;
  } else if (r < 416) {     // Whh [H,H]
    r -= 288; nt = r >> 3; kt = r & 7; KT = 8;
    src = Whh + (size_t)l * H_ * H_; ld = H_;
    dh = base + OWHH; dl = dh + PWHH;
  } else if (r < 440) {     // Whz flat [96, HH]
    r -= 416; nt = r >> 2; kt = r & 3; KT = 4;
    src = Whz + (size_t)l * 3 * E_ * HH_; ld = HH_;
    dh = base + OWHZ; dl = dh + PWHZ;
  } else {                  // Wzd per g: [H, E]
    r -= 440; int g = r >> 4; nt = r & 15; kt = 0; KT = 1;
    src = Wzd + (size_t)(l * 3 + g) * H_ * E_; ld = E_;
    dh = base + OWZD + g * 16 * 512; dl = base + OWZD + PWZD + g * 16 * 512;
  }
  int row = nt * 16 + rowL;
  long dof = ((long)(nt * KT + kt) * 64 + lane) * 8;
  for (int j = 0; j < 8; ++j) {
    int k = kt * 32 + kg + j;
    float v;
    if (special) {
      v = (k < 256) ? Wih_hy[((size_t)l * HH_ + row) * (D_ + H_) + 256 + k]
                    : Whh_hy[((size_t)l * HH_ + row) * HH_ + (k - 256)];
    } else {
      v = src[(size_t)row * ld + k];
    }
    u16 hi, lo;
    split2(v, hi, lo);
    dh[dof + j] = hi;
    dl[dof + j] = lo;
  }
}

// ---------------------------------------------------------------------------
// GEMM: xW[m,0:256], xH[m,0:128] = x[m,0:256] @ {Wih, Wih_hy_x}^T
// ---------------------------------------------------------------------------
__global__ __launch_bounds__(256, 1) void metarnn_gemm(
    const float *__restrict__ x, const u16 *__restrict__ fr,
    float *__restrict__ xW, float *__restrict__ xH) {
  int w = threadIdx.x >> 6, lane = threadIdx.x & 63;
  int m0 = blockIdx.x * 32;
  int rowL = lane & 15, kg = (lane >> 4) << 3;
  f32x4 acc[2][6] = {};
  const u16 *fxw_h = fr + OXW, *fxw_l = fxw_h + PXW;
  const u16 *fxh_h = fr + OXH, *fxh_l = fxh_h + PXH;

  for (int kt = 0; kt < 8; ++kt) {
    bf16x8 ah[2], al[2];
    for (int s = 0; s < 2; ++s) {
      const float *xp = x + (size_t)(m0 + s * 16 + rowL) * 256 + kt * 32 + kg;
      u16x8 vh, vl;
#pragma unroll
      for (int j = 0; j < 8; ++j) {
        u16 hi, lo;
        split2(xp[j], hi, lo);
        vh[j] = hi; vl[j] = lo;
      }
      ah[s] = __builtin_bit_cast(bf16x8, vh);
      al[s] = __builtin_bit_cast(bf16x8, vl);
    }
#pragma unroll
    for (int q = 0; q < 6; ++q) {
      int nt = w * 6 + q;
      long o = (nt < 16) ? ((long)(nt * 8 + kt) * 64 + lane) * 8
                         : ((long)((nt - 16) * 8 + kt) * 64 + lane) * 8;
      const u16 *bh = (nt < 16) ? fxw_h + o : fxh_h + o;
      const u16 *bl = (nt < 16) ? fxw_l + o : fxh_l + o;
      bf16x8 B0 = ldfrag(bh), B1 = ldfrag(bl);
      acc[0][q] = mfma3(ah[0], al[0], B0, B1, acc[0][q]);
      acc[1][q] = mfma3(ah[1], al[1], B0, B1, acc[1][q]);
    }
  }
  for (int s = 0; s < 2; ++s)
    for (int q = 0; q < 6; ++q) {
      int nt = w * 6 + q;
#pragma unroll
      for (int r = 0; r < 4; ++r) {
        int row = m0 + s * 16 + (lane >> 4) * 4 + r;
        if (nt < 16)
          xW[(size_t)row * H_ + nt * 16 + rowL] = acc[s][q][r];
        else
          xH[(size_t)row * HH_ + (nt - 16) * 16 + rowL] = acc[s][q][r];
      }
    }
}

// ---------------------------------------------------------------------------
// scan v2: 16 blocks x 512 threads (8 waves, 2/SIMD). Wave w owns:
//   Whh tiles nt=2w,2w+1 (streamed), HY tile nt=w (streamed),
//   z tile nt=w (resident, w<6), d tiles g x {2w,2w+1} (resident).
// Per step: P1 (aA,aW) | B1 | P2 hh_new | B2 | P3/P4 z | B3 | P5 d, P6 h | B4
// ---------------------------------------------------------------------------
__global__ __launch_bounds__(512, 2) void metarnn_scan(
    const float *__restrict__ xW, const float *__restrict__ xH,
    const u16 *__restrict__ fr, const float *__restrict__ bmain,
    const float *__restrict__ bhy, const float *__restrict__ bz,
    float *__restrict__ y, float *__restrict__ hlast, int layer, int isLast) {
  __shared__ __align__(16) u16 hc_h[12 * 512];
  __shared__ __align__(16) u16 hc_l[12 * 512];
  __shared__ __align__(16) u16 zf_h[3 * 512];
  __shared__ __align__(16) u16 zf_l[3 * 512];

  int tid = threadIdx.x, w = tid >> 6, lane = tid & 63;
  int bs = blockIdx.x * 16;
  int rowL = lane & 15, colG = lane >> 4;

  for (int i = tid; i < 12 * 512; i += 512) { hc_h[i] = 0; hc_l[i] = 0; }
  for (int i = tid; i < 3 * 512; i += 512) { zf_h[i] = 0; zf_l[i] = 0; }

  const u16 *FHY = fr + OHY, *FHYl = FHY + PHY;
  const u16 *FWH = fr + OWHH, *FWHl = FWH + PWHH;
  const u16 *FWZ = fr + OWHZ, *FWZl = FWZ + PWHZ;
  const u16 *FZD = fr + OWZD, *FZDl = FZD + PWZD;

  // ---- resident weights ---------------------------------------------------
  bf16x8 zresH[4], zresL[4];
  {
    int wz = (w < 6) ? w : 0;
#pragma unroll
    for (int kk = 0; kk < 4; ++kk) {
      long o = ((long)(wz * 4 + kk) * 64 + lane) * 8;
      zresH[kk] = ldfrag(FWZ + o);
      zresL[kk] = ldfrag(FWZl + o);
    }
  }
  bf16x8 DH[3][2], DL[3][2];
#pragma unroll
  for (int g = 0; g < 3; ++g)
#pragma unroll
    for (int p = 0; p < 2; ++p) {
      long o = ((long)(g * 16 + 2 * w + p) * 64 + lane) * 8;
      DH[g][p] = ldfrag(FZD + o);
      DL[g][p] = ldfrag(FZDl + o);
    }

  // ---- hoisted biases -----------------------------------------------------
  int c2 = 16 * w + rowL;                       // hyper col (0..127)
  float bhv = bhy[layer * HH_ + c2];
  float bzv = (w < 6) ? bz[layer * 3 * E_ + c2] : 0.0f;
  float bbv[2];
  bbv[0] = bmain[layer * H_ + 32 * w + rowL];
  bbv[1] = bmain[layer * H_ + 32 * w + 16 + rowL];

  // ---- streamed-weight rotating buffers (slot s holds kt == s mod 3) ------
  bf16x8 bWH[3][2], bWL[3][2], bYH[3], bYL[3];
#define LOAD_SLOT(S, KT)                                                      \
  {                                                                           \
    long oy = ((long)(w * 12 + (KT)) * 64 + lane) * 8;                        \
    bYH[S] = ldfrag(FHY + oy);                                                \
    bYL[S] = ldfrag(FHYl + oy);                                               \
    if ((KT) < 8) {                                                           \
      long o0 = ((long)((2 * w) * 8 + (KT)) * 64 + lane) * 8;                 \
      long o1 = ((long)((2 * w + 1) * 8 + (KT)) * 64 + lane) * 8;             \
      bWH[S][0] = ldfrag(FWH + o0); bWL[S][0] = ldfrag(FWHl + o0);            \
      bWH[S][1] = ldfrag(FWH + o1); bWL[S][1] = ldfrag(FWHl + o1);            \
    }                                                                         \
  }
#pragma unroll
  for (int s = 0; s < 3; ++s) LOAD_SLOT(s, s)

  __syncthreads();

  for (int t = 0; t < T_; ++t) {
    // ---- early per-step input loads (consumed in P2/P6; barriers keep
    //      issue here, ~1300 cyc ahead of use) -----------------------------
    float xhv[4], xwv[2][4];
#pragma unroll
    for (int r = 0; r < 4; ++r) {
      size_t row = (size_t)(bs + 4 * colG + r) * T_ + t;
      xhv[r] = xH[row * HH_ + c2];
      xwv[0][r] = xW[row * H_ + 32 * w + rowL];
      xwv[1][r] = xW[row * H_ + 32 * w + 16 + rowL];
    }

    // ---- P1: aA (hcat @ HY^T tile w), aW (h @ Whh^T tiles 2w,2w+1) --------
    f32x4 aA = {}, aW0 = {}, aW1 = {};
#pragma unroll
    for (int j = 0; j < 12; ++j) {
      const int s = j % 3;
      bf16x8 ah = ldfrag(&hc_h[j * 512 + lane * 8]);
      bf16x8 al = ldfrag(&hc_l[j * 512 + lane * 8]);
      aA = mfma3(ah, al, bYH[s], bYL[s], aA);
      if (j < 8) {
        aW0 = mfma3(ah, al, bWH[s][0], bWL[s][0], aW0);
        aW1 = mfma3(ah, al, bWH[s][1], bWL[s][1], aW1);
      }
      if (j < 9) LOAD_SLOT(s, j + 3)      // prefetch kt=j+3 (distance 3)
    }
    __syncthreads();                       // B1 (drains loads; hc kt8-11 free)

    // refill slots 0..2 for next step (ages across P2..P6)
#pragma unroll
    for (int s = 0; s < 3; ++s) LOAD_SLOT(s, s)

    // ---- P2: hh_new = tanh(aA + xH + b_hy) -> hc frags kt 8+(w>>1) --------
    {
      int kfr = 8 + (w >> 1);
      int hb2 = 2 * (w & 1) + (rowL >> 3);
      int j7 = rowL & 7;
#pragma unroll
      for (int r = 0; r < 4; ++r) {
        float v = tanh_fast(aA[r] + xhv[r] + bhv);
        u16 hi, lo;
        split2(v, hi, lo);
        int di = kfr * 512 + ((4 * colG + r) + 16 * hb2) * 8 + j7;
        hc_h[di] = hi;
        hc_l[di] = lo;
      }
    }
    __syncthreads();                       // B2 (hh frags ready)

    // ---- P3/P4: z = hh_new @ Whz^T + bz -> zf frags (waves 0..5) ----------
    if (w < 6) {
      f32x4 aZ = {};
#pragma unroll
      for (int kk = 0; kk < 4; ++kk) {
        bf16x8 ah = ldfrag(&hc_h[(8 + kk) * 512 + lane * 8]);
        bf16x8 al = ldfrag(&hc_l[(8 + kk) * 512 + lane * 8]);
        aZ = mfma3(ah, al, zresH[kk], zresL[kk], aZ);
      }
      int g = c2 >> 5;                     // c2 = 16w+rowL in [0,96)
      int hb3 = 2 * (w & 1) + (rowL >> 3);
      int j7 = rowL & 7;
#pragma unroll
      for (int r = 0; r < 4; ++r) {
        float v = aZ[r] + bzv;
        u16 hi, lo;
        split2(v, hi, lo);
        int di = g * 512 + ((4 * colG + r) + 16 * hb3) * 8 + j7;
        zf_h[di] = hi;
        zf_l[di] = lo;
      }
    }
    __syncthreads();                       // B3 (zf ready)

    // ---- P5: d_g = z @ Wzd_g^T (tiles 2w,2w+1, resident weights) ----------
    f32x4 aD[3][2];
#pragma unroll
    for (int g = 0; g < 3; ++g) {
      bf16x8 zh = ldfrag(&zf_h[g * 512 + lane * 8]);
      bf16x8 zl = ldfrag(&zf_l[g * 512 + lane * 8]);
#pragma unroll
      for (int p = 0; p < 2; ++p) {
        f32x4 zero = {};
        aD[g][p] = mfma3(zh, zl, DH[g][p], DL[g][p], zero);
      }
    }

    // ---- P6: h_new = tanh(d0*xW + d1*hWhh + d2 + b) -> y, hc frags kt=w ---
#pragma unroll
    for (int p = 0; p < 2; ++p) {
      int c = 32 * w + 16 * p + rowL;
      int hb6 = 2 * p + (rowL >> 3);
      int j7 = rowL & 7;
#pragma unroll
      for (int r = 0; r < 4; ++r) {
        int m = 4 * colG + r;
        float aw = (p == 0) ? aW0[r] : aW1[r];
        float arg = aD[0][p][r] * xwv[p][r] + aD[1][p][r] * aw
                    + aD[2][p][r] + bbv[p];
        float h = tanh_fast(arg);
        size_t gi = (size_t)(bs + m) * T_ + t;
        y[gi * H_ + c] = h;
        if (isLast && t == T_ - 1) hlast[(size_t)(bs + m) * H_ + c] = h;
        u16 hi, lo;
        split2(h, hi, lo);
        int di = w * 512 + (m + 16 * hb6) * 8 + j7;
        hc_h[di] = hi;
        hc_l[di] = lo;
      }
    }
    __syncthreads();                       // B4 (h frags ready for next P1)
  }
#undef LOAD_SLOT
}

// ---------------------------------------------------------------------------
extern "C" void kernel_launch(void *const *d_in, const int *in_sizes, int n_in,
                              void *d_out, int out_size, void *d_ws,
                              size_t ws_size, hipStream_t stream) {
  (void)in_sizes; (void)n_in; (void)out_size; (void)ws_size;
  const float *input  = (const float *)d_in[0];
  const float *Wih    = (const float *)d_in[1];
  const float *Whh    = (const float *)d_in[2];
  const float *b      = (const float *)d_in[3];
  const float *Wih_hy = (const float *)d_in[4];
  const float *Whh_hy = (const float *)d_in[5];
  const float *b_hy   = (const float *)d_in[6];
  const float *Whz    = (const float *)d_in[7];
  const float *bz     = (const float *)d_in[8];
  const float *Wzd    = (const float *)d_in[9];

  float *out = (float *)d_out;
  float *xW = (float *)((char *)d_ws + WS_XW);
  float *xH = (float *)((char *)d_ws + WS_XH);
  u16 *fr = (u16 *)((char *)d_ws + WS_FR);
  float *hlast = out + (size_t)BT * H_;

  metarnn_prep<<<dim3(244), dim3(256), 0, stream>>>(Wih, Whh, Wih_hy, Whh_hy,
                                                    Whz, Wzd, fr);
  for (int l = 0; l < 2; ++l) {
    const float *xsrc = (l == 0) ? input : out;   // layer1 reads layer0 output
    const u16 *frl = fr + (size_t)l * LSTRIDE;
    metarnn_gemm<<<dim3(BT / 32), dim3(256), 0, stream>>>(xsrc, frl, xW, xH);
    metarnn_scan<<<dim3(16), dim3(512), 0, stream>>>(
        xW, xH, frl, b, b_hy, bz, out, hlast, l, (l == 1) ? 1 : 0);
  }
}

// Round 3
// 9033.356 us; speedup vs baseline: 1.9396x; 1.3178x over previous
//
#include <hip/hip_runtime.h>

// ---------------------------------------------------------------------------
// MetaRNN (HyperNetwork-conditioned RNN), MI355X gfx950.  v3
//   per layer:
//     1) GEMM (MFMA, split-bf16 x3): xW = x @ Wih^T, xH = x @ Wih_hy_x^T
//     2) scan: 16 blocks x 512 thr (8 waves, 2/SIMD).
//        v3: raw barriers (no vmcnt(0) drain) so weight prefetches stay in
//        flight across phases; Whh-lo register-resident; HY-hi in LDS
//        (loaded once); stream per step = Whh-hi + HY-lo = 224 KB from L2.
//        Split-bf16 3-term products, same accumulation order as v1/v2
//        (absmax 0.0039 validated).
// ---------------------------------------------------------------------------

#define DEVI __device__ __forceinline__

typedef __bf16 bf16x8 __attribute__((ext_vector_type(8)));
typedef float f32x4 __attribute__((ext_vector_type(4)));
typedef unsigned short u16;
typedef unsigned int u32;
typedef u32 u32x4 __attribute__((ext_vector_type(4)));
typedef u16 u16x8 __attribute__((ext_vector_type(8)));

constexpr int B_ = 256, T_ = 512, D_ = 256, H_ = 256, HH_ = 128, E_ = 32;
constexpr int BT = B_ * T_;

// fragment-buffer offsets (u16 elements), per layer
constexpr int OXW = 0,      PXW = 16 * 8 * 512;   // Wih      [16nt][8kt]
constexpr int OXH = 131072, PXH = 8 * 8 * 512;    // Wih_hy_x [8nt][8kt]
constexpr int OHY = 196608, PHY = 8 * 12 * 512;   // [U_hy|Whh_hy] [8nt][12kt]
constexpr int OWHH = 294912, PWHH = 16 * 8 * 512; // Whh      [16nt][8kt]
constexpr int OWHZ = 425984, PWHZ = 6 * 4 * 512;  // Whz flat [6nt][4kt]
constexpr int OWZD = 450560, PWZD = 48 * 512;     // Wzd      [3g][16nt][1kt]
constexpr int LSTRIDE = 499712;                   // u16 per layer

constexpr size_t WS_XW = 0;
constexpr size_t WS_XH = (size_t)BT * H_ * 4;
constexpr size_t WS_FR = WS_XH + (size_t)BT * HH_ * 4;

DEVI u16 f2bf(float v) {            // round-to-nearest-even fp32 -> bf16 bits
  u32 u = __float_as_uint(v);
  u += 0x7fffu + ((u >> 16) & 1u);
  return (u16)(u >> 16);
}
DEVI float bf2f(u16 s) { return __uint_as_float(((u32)s) << 16); }
DEVI void split2(float v, u16 &hi, u16 &lo) {
  hi = f2bf(v);
  lo = f2bf(v - bf2f(hi));          // exact subtraction
}
DEVI bf16x8 ldfrag(const u16 *p) {
  u32x4 v = *reinterpret_cast<const u32x4 *>(p);
  return __builtin_bit_cast(bf16x8, v);
}
DEVI f32x4 mfma3(bf16x8 ah, bf16x8 al, bf16x8 bh, bf16x8 bl, f32x4 c) {
  c = __builtin_amdgcn_mfma_f32_16x16x32_bf16(ah, bh, c, 0, 0, 0);
  c = __builtin_amdgcn_mfma_f32_16x16x32_bf16(ah, bl, c, 0, 0, 0);
  c = __builtin_amdgcn_mfma_f32_16x16x32_bf16(al, bh, c, 0, 0, 0);
  return c;
}
DEVI float tanh_fast(float x) {
  float e = __expf(2.0f * x);       // inf-safe: ->1 / ->-1 at extremes
  return 1.0f - 2.0f / (e + 1.0f);
}
// Raw barrier: LDS ordering enforced (lgkmcnt(0)), but vmem loads stay in
// flight across it (no vmcnt(0) drain as with __syncthreads()).
DEVI void block_sync() {
  asm volatile("s_waitcnt lgkmcnt(0)\n\ts_barrier" ::: "memory");
}

// ---------------------------------------------------------------------------
// prep: split all weights to bf16 hi/lo and lay out as 16x16x32 B-fragments.
// fragment: element j, lane l  <-  W[nt*16 + (l&15), kt*32 + (l>>4)*8 + j]
// ---------------------------------------------------------------------------
__global__ void metarnn_prep(const float *__restrict__ Wih,
                             const float *__restrict__ Whh,
                             const float *__restrict__ Wih_hy,
                             const float *__restrict__ Whh_hy,
                             const float *__restrict__ Whz,
                             const float *__restrict__ Wzd,
                             u16 *__restrict__ fr) {
  int gid = blockIdx.x * 256 + threadIdx.x;
  int lane = gid & 63;
  int e = gid >> 6;
  if (e >= 2 * 488) return;
  int l = e / 488, r = e - l * 488;
  u16 *base = fr + (size_t)l * LSTRIDE;
  int rowL = lane & 15, kg = (lane >> 4) << 3;

  const float *src = nullptr;
  int ld = 0, nt = 0, kt = 0, KT = 1, special = 0;
  u16 *dh = nullptr, *dl = nullptr;
  if (r < 128) {            // Wih [H,D]
    nt = r >> 3; kt = r & 7; KT = 8;
    src = Wih + (size_t)l * H_ * D_; ld = D_;
    dh = base + OXW; dl = dh + PXW;
  } else if (r < 192) {     // Wih_hy x-part [HH, 0:256]
    r -= 128; nt = r >> 3; kt = r & 7; KT = 8;
    src = Wih_hy + (size_t)l * HH_ * (D_ + H_); ld = D_ + H_;
    dh = base + OXH; dl = dh + PXH;
  } else if (r < 288) {     // concat [U_hy | Whh_hy]  [HH, 384]
    r -= 192; nt = r / 12; kt = r - nt * 12; KT = 12; special = 1;
    dh = base + OHY; dl = dh + PHY;
  } else if (r < 416) {     // Whh [H,H]
    r -= 288; nt = r >> 3; kt = r & 7; KT = 8;
    src = Whh + (size_t)l * H_ * H_; ld = H_;
    dh = base + OWHH; dl = dh + PWHH;
  } else if (r < 440) {     // Whz flat [96, HH]
    r -= 416; nt = r >> 2; kt = r & 3; KT = 4;
    src = Whz + (size_t)l * 3 * E_ * HH_; ld = HH_;
    dh = base + OWHZ; dl = dh + PWHZ;
  } else {                  // Wzd per g: [H, E]
    r -= 440; int g = r >> 4; nt = r & 15; kt = 0; KT = 1;
    src = Wzd + (size_t)(l * 3 + g) * H_ * E_; ld = E_;
    dh = base + OWZD + g * 16 * 512; dl = base + OWZD + PWZD + g * 16 * 512;
  }
  int row = nt * 16 + rowL;
  long dof = ((long)(nt * KT + kt) * 64 + lane) * 8;
  for (int j = 0; j < 8; ++j) {
    int k = kt * 32 + kg + j;
    float v;
    if (special) {
      v = (k < 256) ? Wih_hy[((size_t)l * HH_ + row) * (D_ + H_) + 256 + k]
                    : Whh_hy[((size_t)l * HH_ + row) * HH_ + (k - 256)];
    } else {
      v = src[(size_t)row * ld + k];
    }
    u16 hi, lo;
    split2(v, hi, lo);
    dh[dof + j] = hi;
    dl[dof + j] = lo;
  }
}

// ---------------------------------------------------------------------------
// GEMM: xW[m,0:256], xH[m,0:128] = x[m,0:256] @ {Wih, Wih_hy_x}^T
// ---------------------------------------------------------------------------
__global__ __launch_bounds__(256, 1) void metarnn_gemm(
    const float *__restrict__ x, const u16 *__restrict__ fr,
    float *__restrict__ xW, float *__restrict__ xH) {
  int w = threadIdx.x >> 6, lane = threadIdx.x & 63;
  int m0 = blockIdx.x * 32;
  int rowL = lane & 15, kg = (lane >> 4) << 3;
  f32x4 acc[2][6] = {};
  const u16 *fxw_h = fr + OXW, *fxw_l = fxw_h + PXW;
  const u16 *fxh_h = fr + OXH, *fxh_l = fxh_h + PXH;

  for (int kt = 0; kt < 8; ++kt) {
    bf16x8 ah[2], al[2];
    for (int s = 0; s < 2; ++s) {
      const float *xp = x + (size_t)(m0 + s * 16 + rowL) * 256 + kt * 32 + kg;
      u16x8 vh, vl;
#pragma unroll
      for (int j = 0; j < 8; ++j) {
        u16 hi, lo;
        split2(xp[j], hi, lo);
        vh[j] = hi; vl[j] = lo;
      }
      ah[s] = __builtin_bit_cast(bf16x8, vh);
      al[s] = __builtin_bit_cast(bf16x8, vl);
    }
#pragma unroll
    for (int q = 0; q < 6; ++q) {
      int nt = w * 6 + q;
      long o = (nt < 16) ? ((long)(nt * 8 + kt) * 64 + lane) * 8
                         : ((long)((nt - 16) * 8 + kt) * 64 + lane) * 8;
      const u16 *bh = (nt < 16) ? fxw_h + o : fxh_h + o;
      const u16 *bl = (nt < 16) ? fxw_l + o : fxh_l + o;
      bf16x8 B0 = ldfrag(bh), B1 = ldfrag(bl);
      acc[0][q] = mfma3(ah[0], al[0], B0, B1, acc[0][q]);
      acc[1][q] = mfma3(ah[1], al[1], B0, B1, acc[1][q]);
    }
  }
  for (int s = 0; s < 2; ++s)
    for (int q = 0; q < 6; ++q) {
      int nt = w * 6 + q;
#pragma unroll
      for (int r = 0; r < 4; ++r) {
        int row = m0 + s * 16 + (lane >> 4) * 4 + r;
        if (nt < 16)
          xW[(size_t)row * H_ + nt * 16 + rowL] = acc[s][q][r];
        else
          xH[(size_t)row * HH_ + (nt - 16) * 16 + rowL] = acc[s][q][r];
      }
    }
}

// ---------------------------------------------------------------------------
// scan v3: 16 blocks x 512 threads (8 waves, 2/SIMD). Wave w owns:
//   Whh tiles nt=2w,2w+1 (hi streamed, lo register-resident),
//   HY tile nt=w (hi in LDS, lo streamed),
//   z tile nt=w (resident, w<6), d tiles g x {2w,2w+1} (resident).
// Per step: P1 (aA,aW) | B1 | P2 hh_new | B2 | P3/P4 z | B3 | P5+P6 h | B4
// ---------------------------------------------------------------------------
__global__ __launch_bounds__(512, 2) void metarnn_scan(
    const float *__restrict__ xW, const float *__restrict__ xH,
    const u16 *__restrict__ fr, const float *__restrict__ bmain,
    const float *__restrict__ bhy, const float *__restrict__ bz,
    float *__restrict__ y, float *__restrict__ hlast, int layer, int isLast) {
  __shared__ __align__(16) u16 hc_h[12 * 512];
  __shared__ __align__(16) u16 hc_l[12 * 512];
  __shared__ __align__(16) u16 zf_h[3 * 512];
  __shared__ __align__(16) u16 zf_l[3 * 512];
  __shared__ __align__(16) u16 hy_lds[8 * 12 * 512];   // HY-hi, 96 KB

  int tid = threadIdx.x, w = tid >> 6, lane = tid & 63;
  int bs = blockIdx.x * 16;
  int rowL = lane & 15, colG = lane >> 4;

  const u16 *FHY = fr + OHY, *FHYl = FHY + PHY;
  const u16 *FWH = fr + OWHH, *FWHl = FWH + PWHH;
  const u16 *FWZ = fr + OWHZ, *FWZl = FWZ + PWHZ;
  const u16 *FZD = fr + OWZD, *FZDl = FZD + PWZD;

  for (int i = tid; i < 12 * 512; i += 512) { hc_h[i] = 0; hc_l[i] = 0; }
  for (int i = tid; i < 3 * 512; i += 512) { zf_h[i] = 0; zf_l[i] = 0; }
  // HY-hi -> LDS (once)
  for (int i = tid; i < 8 * 12 * 512 / 8; i += 512) {
    *reinterpret_cast<u32x4 *>(&hy_lds[(size_t)i * 8]) =
        *reinterpret_cast<const u32x4 *>(FHY + (size_t)i * 8);
  }

  // ---- register-resident weights -----------------------------------------
  bf16x8 zresH[4], zresL[4];
  {
    int wz = (w < 6) ? w : 0;
#pragma unroll
    for (int kk = 0; kk < 4; ++kk) {
      long o = ((long)(wz * 4 + kk) * 64 + lane) * 8;
      zresH[kk] = ldfrag(FWZ + o);
      zresL[kk] = ldfrag(FWZl + o);
    }
  }
  bf16x8 DH[3][2], DL[3][2];
#pragma unroll
  for (int g = 0; g < 3; ++g)
#pragma unroll
    for (int p = 0; p < 2; ++p) {
      long o = ((long)(g * 16 + 2 * w + p) * 64 + lane) * 8;
      DH[g][p] = ldfrag(FZD + o);
      DL[g][p] = ldfrag(FZDl + o);
    }
  bf16x8 RWL[2][8];                       // Whh-lo resident (64 VGPR)
#pragma unroll
  for (int p = 0; p < 2; ++p)
#pragma unroll
    for (int kt = 0; kt < 8; ++kt) {
      long o = ((long)((2 * w + p) * 8 + kt) * 64 + lane) * 8;
      RWL[p][kt] = ldfrag(FWHl + o);
    }

  // ---- hoisted biases -----------------------------------------------------
  int c2 = 16 * w + rowL;                       // hyper col (0..127)
  float bhv = bhy[layer * HH_ + c2];
  float bzv = (w < 6) ? bz[layer * 3 * E_ + c2] : 0.0f;
  float bbv[2];
  bbv[0] = bmain[layer * H_ + 32 * w + rowL];
  bbv[1] = bmain[layer * H_ + 32 * w + 16 + rowL];

  // ---- streamed-weight rotating buffers (slot s holds kt == s mod 3) ------
  // per slot: HY-lo 1 frag + Whh-hi 2 frags (kt<8)
  bf16x8 bWH[3][2], bYL[3];
#define LOAD_SLOT(S, KT)                                                      \
  {                                                                           \
    long oy = ((long)(w * 12 + (KT)) * 64 + lane) * 8;                        \
    bYL[S] = ldfrag(FHYl + oy);                                               \
    if ((KT) < 8) {                                                           \
      long o0 = ((long)((2 * w) * 8 + (KT)) * 64 + lane) * 8;                 \
      long o1 = ((long)((2 * w + 1) * 8 + (KT)) * 64 + lane) * 8;             \
      bWH[S][0] = ldfrag(FWH + o0);                                           \
      bWH[S][1] = ldfrag(FWH + o1);                                           \
    }                                                                         \
  }
#pragma unroll
  for (int s = 0; s < 3; ++s) LOAD_SLOT(s, s)

  __syncthreads();                        // once; full drain acceptable here

  for (int t = 0; t < T_; ++t) {
    // ---- early per-step input loads (consumed in P2/P6) -------------------
    float xhv[4], xwv[2][4];
#pragma unroll
    for (int r = 0; r < 4; ++r) {
      size_t row = (size_t)(bs + 4 * colG + r) * T_ + t;
      xhv[r] = xH[row * HH_ + c2];
      xwv[0][r] = xW[row * H_ + 32 * w + rowL];
      xwv[1][r] = xW[row * H_ + 32 * w + 16 + rowL];
    }

    // ---- P1: aA (hcat @ HY^T tile w), aW (h @ Whh^T tiles 2w,2w+1) --------
    f32x4 aA = {}, aW0 = {}, aW1 = {};
#pragma unroll
    for (int j = 0; j < 12; ++j) {
      const int s = j % 3;
      bf16x8 ah = ldfrag(&hc_h[j * 512 + lane * 8]);
      bf16x8 al = ldfrag(&hc_l[j * 512 + lane * 8]);
      bf16x8 yh = ldfrag(&hy_lds[(w * 12 + j) * 512 + lane * 8]);
      aA = mfma3(ah, al, yh, bYL[s], aA);
      if (j < 8) {
        aW0 = mfma3(ah, al, bWH[s][0], RWL[0][j], aW0);
        aW1 = mfma3(ah, al, bWH[s][1], RWL[1][j], aW1);
      }
      if (j < 9) LOAD_SLOT(s, j + 3)      // prefetch kt=j+3 (distance 3)
    }
    block_sync();                          // B1 (vmem loads keep flying)

    // refill slots 0..2 for next step (in flight across B2..B4)
#pragma unroll
    for (int s = 0; s < 3; ++s) LOAD_SLOT(s, s)

    // ---- P2: hh_new = tanh(aA + xH + b_hy) -> hc frags kt 8+(w>>1) --------
    {
      int kfr = 8 + (w >> 1);
      int hb2 = 2 * (w & 1) + (rowL >> 3);
      int j7 = rowL & 7;
#pragma unroll
      for (int r = 0; r < 4; ++r) {
        float v = tanh_fast(aA[r] + xhv[r] + bhv);
        u16 hi, lo;
        split2(v, hi, lo);
        int di = kfr * 512 + ((4 * colG + r) + 16 * hb2) * 8 + j7;
        hc_h[di] = hi;
        hc_l[di] = lo;
      }
    }
    block_sync();                          // B2 (hh frags ready)

    // ---- P3/P4: z = hh_new @ Whz^T + bz -> zf frags (waves 0..5) ----------
    if (w < 6) {
      f32x4 aZ = {};
#pragma unroll
      for (int kk = 0; kk < 4; ++kk) {
        bf16x8 ah = ldfrag(&hc_h[(8 + kk) * 512 + lane * 8]);
        bf16x8 al = ldfrag(&hc_l[(8 + kk) * 512 + lane * 8]);
        aZ = mfma3(ah, al, zresH[kk], zresL[kk], aZ);
      }
      int g = c2 >> 5;                     // c2 = 16w+rowL in [0,96)
      int hb3 = 2 * (w & 1) + (rowL >> 3);
      int j7 = rowL & 7;
#pragma unroll
      for (int r = 0; r < 4; ++r) {
        float v = aZ[r] + bzv;
        u16 hi, lo;
        split2(v, hi, lo);
        int di = g * 512 + ((4 * colG + r) + 16 * hb3) * 8 + j7;
        zf_h[di] = hi;
        zf_l[di] = lo;
      }
    }
    block_sync();                          // B3 (zf ready)

    // ---- P5+P6: d_g = z @ Wzd_g^T, accumulate h-arg sequentially over g ---
    float arg[2][4];
#pragma unroll
    for (int p = 0; p < 2; ++p)
#pragma unroll
      for (int r = 0; r < 4; ++r) arg[p][r] = bbv[p];
#pragma unroll
    for (int g = 0; g < 3; ++g) {
      bf16x8 zh = ldfrag(&zf_h[g * 512 + lane * 8]);
      bf16x8 zl = ldfrag(&zf_l[g * 512 + lane * 8]);
#pragma unroll
      for (int p = 0; p < 2; ++p) {
        f32x4 zero = {};
        f32x4 dg = mfma3(zh, zl, DH[g][p], DL[g][p], zero);
#pragma unroll
        for (int r = 0; r < 4; ++r) {
          float mul = (g == 0) ? xwv[p][r]
                    : (g == 1) ? ((p == 0) ? aW0[r] : aW1[r]) : 1.0f;
          arg[p][r] += dg[r] * mul;
        }
      }
    }
#pragma unroll
    for (int p = 0; p < 2; ++p) {
      int c = 32 * w + 16 * p + rowL;
      int hb6 = 2 * p + (rowL >> 3);
      int j7 = rowL & 7;
#pragma unroll
      for (int r = 0; r < 4; ++r) {
        int m = 4 * colG + r;
        float h = tanh_fast(arg[p][r]);
        size_t gi = (size_t)(bs + m) * T_ + t;
        y[gi * H_ + c] = h;
        if (isLast && t == T_ - 1) hlast[(size_t)(bs + m) * H_ + c] = h;
        u16 hi, lo;
        split2(h, hi, lo);
        int di = w * 512 + (m + 16 * hb6) * 8 + j7;
        hc_h[di] = hi;
        hc_l[di] = lo;
      }
    }
    block_sync();                          // B4 (h frags ready for next P1)
  }
#undef LOAD_SLOT
}

// ---------------------------------------------------------------------------
extern "C" void kernel_launch(void *const *d_in, const int *in_sizes, int n_in,
                              void *d_out, int out_size, void *d_ws,
                              size_t ws_size, hipStream_t stream) {
  (void)in_sizes; (void)n_in; (void)out_size; (void)ws_size;
  const float *input  = (const float *)d_in[0];
  const float *Wih    = (const float *)d_in[1];
  const float *Whh    = (const float *)d_in[2];
  const float *b      = (const float *)d_in[3];
  const float *Wih_hy = (const float *)d_in[4];
  const float *Whh_hy = (const float *)d_in[5];
  const float *b_hy   = (const float *)d_in[6];
  const float *Whz    = (const float *)d_in[7];
  const float *bz     = (const float *)d_in[8];
  const float *Wzd    = (const float *)d_in[9];

  float *out = (float *)d_out;
  float *xW = (float *)((char *)d_ws + WS_XW);
  float *xH = (float *)((char *)d_ws + WS_XH);
  u16 *fr = (u16 *)((char *)d_ws + WS_FR);
  float *hlast = out + (size_t)BT * H_;

  metarnn_prep<<<dim3(244), dim3(256), 0, stream>>>(Wih, Whh, Wih_hy, Whh_hy,
                                                    Whz, Wzd, fr);
  for (int l = 0; l < 2; ++l) {
    const float *xsrc = (l == 0) ? input : out;   // layer1 reads layer0 output
    const u16 *frl = fr + (size_t)l * LSTRIDE;
    metarnn_gemm<<<dim3(BT / 32), dim3(256), 0, stream>>>(xsrc, frl, xW, xH);
    metarnn_scan<<<dim3(16), dim3(512), 0, stream>>>(
        xW, xH, frl, b, b_hy, bz, out, hlast, l, (l == 1) ? 1 : 0);
  }
}

// Round 4
// 8796.287 us; speedup vs baseline: 1.9919x; 1.0270x over previous
//
#include <hip/hip_runtime.h>

// ---------------------------------------------------------------------------
// MetaRNN (HyperNetwork-conditioned RNN), MI355X gfx950.  v4
//   per layer:
//     1) GEMM (MFMA, split-bf16 x3): xW = x @ Wih^T, xH = x @ Wih_hy_x^T
//     2) scan: 16 blocks x 512 thr (8 waves, 2/SIMD).
//        v4: weights PINNED in VGPRs via empty-asm (compiler cannot
//        rematerialize) -> no in-loop L2 loads for Whh-lo/Whz/Wzd; hh frags
//        double-buffered by t-parity -> 3 barriers/step; HY-hi in LDS;
//        streamed per step = Whh-hi + HY-lo (28 KB/wave) via 3-slot rotation.
//        Split-bf16 3-term products (absmax 0.0039 validated v1-v3).
// ---------------------------------------------------------------------------

#define DEVI __device__ __forceinline__

typedef __bf16 bf16x8 __attribute__((ext_vector_type(8)));
typedef float f32x4 __attribute__((ext_vector_type(4)));
typedef unsigned short u16;
typedef unsigned int u32;
typedef u32 u32x4 __attribute__((ext_vector_type(4)));
typedef u16 u16x8 __attribute__((ext_vector_type(8)));

constexpr int B_ = 256, T_ = 512, D_ = 256, H_ = 256, HH_ = 128, E_ = 32;
constexpr int BT = B_ * T_;

// fragment-buffer offsets (u16 elements), per layer
constexpr int OXW = 0,      PXW = 16 * 8 * 512;   // Wih      [16nt][8kt]
constexpr int OXH = 131072, PXH = 8 * 8 * 512;    // Wih_hy_x [8nt][8kt]
constexpr int OHY = 196608, PHY = 8 * 12 * 512;   // [U_hy|Whh_hy] [8nt][12kt]
constexpr int OWHH = 294912, PWHH = 16 * 8 * 512; // Whh      [16nt][8kt]
constexpr int OWHZ = 425984, PWHZ = 6 * 4 * 512;  // Whz flat [6nt][4kt]
constexpr int OWZD = 450560, PWZD = 48 * 512;     // Wzd      [3g][16nt][1kt]
constexpr int LSTRIDE = 499712;                   // u16 per layer

constexpr size_t WS_XW = 0;
constexpr size_t WS_XH = (size_t)BT * H_ * 4;
constexpr size_t WS_FR = WS_XH + (size_t)BT * HH_ * 4;

DEVI u16 f2bf(float v) {            // round-to-nearest-even fp32 -> bf16 bits
  u32 u = __float_as_uint(v);
  u += 0x7fffu + ((u >> 16) & 1u);
  return (u16)(u >> 16);
}
DEVI float bf2f(u16 s) { return __uint_as_float(((u32)s) << 16); }
DEVI void split2(float v, u16 &hi, u16 &lo) {
  hi = f2bf(v);
  lo = f2bf(v - bf2f(hi));          // exact subtraction
}
DEVI bf16x8 ldfrag(const u16 *p) {
  u32x4 v = *reinterpret_cast<const u32x4 *>(p);
  return __builtin_bit_cast(bf16x8, v);
}
// Pin a fragment in VGPRs: opaque to the optimizer -> cannot rematerialize
// the originating load; value stays register-resident.
DEVI void pin(bf16x8 &x) {
  u32x4 t = __builtin_bit_cast(u32x4, x);
  asm volatile("" : "+v"(t));
  x = __builtin_bit_cast(bf16x8, t);
}
DEVI f32x4 mfma3(bf16x8 ah, bf16x8 al, bf16x8 bh, bf16x8 bl, f32x4 c) {
  c = __builtin_amdgcn_mfma_f32_16x16x32_bf16(ah, bh, c, 0, 0, 0);
  c = __builtin_amdgcn_mfma_f32_16x16x32_bf16(ah, bl, c, 0, 0, 0);
  c = __builtin_amdgcn_mfma_f32_16x16x32_bf16(al, bh, c, 0, 0, 0);
  return c;
}
DEVI float tanh_fast(float x) {
  float e = __expf(2.0f * x);       // inf-safe: ->1 / ->-1 at extremes
  return 1.0f - 2.0f / (e + 1.0f);
}
// Raw barrier: LDS ordering enforced (lgkmcnt(0)), vmem loads stay in flight.
DEVI void block_sync() {
  asm volatile("s_waitcnt lgkmcnt(0)\n\ts_barrier" ::: "memory");
}

// ---------------------------------------------------------------------------
// prep: split all weights to bf16 hi/lo and lay out as 16x16x32 B-fragments.
// fragment: element j, lane l  <-  W[nt*16 + (l&15), kt*32 + (l>>4)*8 + j]
// ---------------------------------------------------------------------------
__global__ void metarnn_prep(const float *__restrict__ Wih,
                             const float *__restrict__ Whh,
                             const float *__restrict__ Wih_hy,
                             const float *__restrict__ Whh_hy,
                             const float *__restrict__ Whz,
                             const float *__restrict__ Wzd,
                             u16 *__restrict__ fr) {
  int gid = blockIdx.x * 256 + threadIdx.x;
  int lane = gid & 63;
  int e = gid >> 6;
  if (e >= 2 * 488) return;
  int l = e / 488, r = e - l * 488;
  u16 *base = fr + (size_t)l * LSTRIDE;
  int rowL = lane & 15, kg = (lane >> 4) << 3;

  const float *src = nullptr;
  int ld = 0, nt = 0, kt = 0, KT = 1, special = 0;
  u16 *dh = nullptr, *dl = nullptr;
  if (r < 128) {            // Wih [H,D]
    nt = r >> 3; kt = r & 7; KT = 8;
    src = Wih + (size_t)l * H_ * D_; ld = D_;
    dh = base + OXW; dl = dh + PXW;
  } else if (r < 192) {     // Wih_hy x-part [HH, 0:256]
    r -= 128; nt = r >> 3; kt = r & 7; KT = 8;
    src = Wih_hy + (size_t)l * HH_ * (D_ + H_); ld = D_ + H_;
    dh = base + OXH; dl = dh + PXH;
  } else if (r < 288) {     // concat [U_hy | Whh_hy]  [HH, 384]
    r -= 192; nt = r / 12; kt = r - nt * 12; KT = 12; special = 1;
    dh = base + OHY; dl = dh + PHY;
  } else if (r < 416) {     // Whh [H,H]
    r -= 288; nt = r >> 3; kt = r & 7; KT = 8;
    src = Whh + (size_t)l * H_ * H_; ld = H_;
    dh = base + OWHH; dl = dh + PWHH;
  } else if (r < 440) {     // Whz flat [96, HH]
    r -= 416; nt = r >> 2; kt = r & 3; KT = 4;
    src = Whz + (size_t)l * 3 * E_ * HH_; ld = HH_;
    dh = base + OWHZ; dl = dh + PWHZ;
  } else {                  // Wzd per g: [H, E]
    r -= 440; int g = r >> 4; nt = r & 15; kt = 0; KT = 1;
    src = Wzd + (size_t)(l * 3 + g) * H_ * E_; ld = E_;
    dh = base + OWZD + g * 16 * 512; dl = base + OWZD + PWZD + g * 16 * 512;
  }
  int row = nt * 16 + rowL;
  long dof = ((long)(nt * KT + kt) * 64 + lane) * 8;
  for (int j = 0; j < 8; ++j) {
    int k = kt * 32 + kg + j;
    float v;
    if (special) {
      v = (k < 256) ? Wih_hy[((size_t)l * HH_ + row) * (D_ + H_) + 256 + k]
                    : Whh_hy[((size_t)l * HH_ + row) * HH_ + (k - 256)];
    } else {
      v = src[(size_t)row * ld + k];
    }
    u16 hi, lo;
    split2(v, hi, lo);
    dh[dof + j] = hi;
    dl[dof + j] = lo;
  }
}

// ---------------------------------------------------------------------------
// GEMM: xW[m,0:256], xH[m,0:128] = x[m,0:256] @ {Wih, Wih_hy_x}^T
// ---------------------------------------------------------------------------
__global__ __launch_bounds__(256, 1) void metarnn_gemm(
    const float *__restrict__ x, const u16 *__restrict__ fr,
    float *__restrict__ xW, float *__restrict__ xH) {
  int w = threadIdx.x >> 6, lane = threadIdx.x & 63;
  int m0 = blockIdx.x * 32;
  int rowL = lane & 15, kg = (lane >> 4) << 3;
  f32x4 acc[2][6] = {};
  const u16 *fxw_h = fr + OXW, *fxw_l = fxw_h + PXW;
  const u16 *fxh_h = fr + OXH, *fxh_l = fxh_h + PXH;

  for (int kt = 0; kt < 8; ++kt) {
    bf16x8 ah[2], al[2];
    for (int s = 0; s < 2; ++s) {
      const float *xp = x + (size_t)(m0 + s * 16 + rowL) * 256 + kt * 32 + kg;
      u16x8 vh, vl;
#pragma unroll
      for (int j = 0; j < 8; ++j) {
        u16 hi, lo;
        split2(xp[j], hi, lo);
        vh[j] = hi; vl[j] = lo;
      }
      ah[s] = __builtin_bit_cast(bf16x8, vh);
      al[s] = __builtin_bit_cast(bf16x8, vl);
    }
#pragma unroll
    for (int q = 0; q < 6; ++q) {
      int nt = w * 6 + q;
      long o = (nt < 16) ? ((long)(nt * 8 + kt) * 64 + lane) * 8
                         : ((long)((nt - 16) * 8 + kt) * 64 + lane) * 8;
      const u16 *bh = (nt < 16) ? fxw_h + o : fxh_h + o;
      const u16 *bl = (nt < 16) ? fxw_l + o : fxh_l + o;
      bf16x8 B0 = ldfrag(bh), B1 = ldfrag(bl);
      acc[0][q] = mfma3(ah[0], al[0], B0, B1, acc[0][q]);
      acc[1][q] = mfma3(ah[1], al[1], B0, B1, acc[1][q]);
    }
  }
  for (int s = 0; s < 2; ++s)
    for (int q = 0; q < 6; ++q) {
      int nt = w * 6 + q;
#pragma unroll
      for (int r = 0; r < 4; ++r) {
        int row = m0 + s * 16 + (lane >> 4) * 4 + r;
        if (nt < 16)
          xW[(size_t)row * H_ + nt * 16 + rowL] = acc[s][q][r];
        else
          xH[(size_t)row * HH_ + (nt - 16) * 16 + rowL] = acc[s][q][r];
      }
    }
}

// ---------------------------------------------------------------------------
// scan v4: 16 blocks x 512 threads (8 waves, 2/SIMD). Wave w owns:
//   Whh tiles nt=2w,2w+1 (hi streamed, lo PINNED), HY tile nt=w (hi LDS,
//   lo streamed), z tile nt=w (PINNED, w<6), d tiles g x {2w,2w+1} (PINNED).
// Per step: P1(aA,aW) P2(hh->hhb[pr]) | BA | P3/P4 z | BB | P5+P6 h | BC
// ---------------------------------------------------------------------------
__global__ __launch_bounds__(512, 2) void metarnn_scan(
    const float *__restrict__ xW, const float *__restrict__ xH,
    const u16 *__restrict__ fr, const float *__restrict__ bmain,
    const float *__restrict__ bhy, const float *__restrict__ bz,
    float *__restrict__ y, float *__restrict__ hlast, int layer, int isLast) {
  __shared__ __align__(16) u16 hc_h[8 * 512];        // h frags kt0..7
  __shared__ __align__(16) u16 hc_l[8 * 512];
  __shared__ __align__(16) u16 hhb_h[2][4 * 512];    // hh frags, t-parity dbuf
  __shared__ __align__(16) u16 hhb_l[2][4 * 512];
  __shared__ __align__(16) u16 zf_h[3 * 512];
  __shared__ __align__(16) u16 zf_l[3 * 512];
  __shared__ __align__(16) u16 hy_lds[8 * 12 * 512]; // HY-hi, 96 KB

  int tid = threadIdx.x, w = tid >> 6, lane = tid & 63;
  int bs = blockIdx.x * 16;
  int rowL = lane & 15, colG = lane >> 4;

  const u16 *FHY = fr + OHY, *FHYl = FHY + PHY;
  const u16 *FWH = fr + OWHH, *FWHl = FWH + PWHH;
  const u16 *FWZ = fr + OWHZ, *FWZl = FWZ + PWHZ;
  const u16 *FZD = fr + OWZD, *FZDl = FZD + PWZD;

  for (int i = tid; i < 8 * 512; i += 512) { hc_h[i] = 0; hc_l[i] = 0; }
  for (int i = tid; i < 4 * 512; i += 512) {
    hhb_h[0][i] = 0; hhb_l[0][i] = 0; hhb_h[1][i] = 0; hhb_l[1][i] = 0;
  }
  for (int i = tid; i < 3 * 512; i += 512) { zf_h[i] = 0; zf_l[i] = 0; }
  // HY-hi -> LDS (once)
  for (int i = tid; i < 8 * 12 * 512 / 8; i += 512) {
    *reinterpret_cast<u32x4 *>(&hy_lds[(size_t)i * 8]) =
        *reinterpret_cast<const u32x4 *>(FHY + (size_t)i * 8);
  }

  // ---- PINNED register-resident weights ----------------------------------
  bf16x8 zresH[4], zresL[4];
  {
    int wz = (w < 6) ? w : 0;
#pragma unroll
    for (int kk = 0; kk < 4; ++kk) {
      long o = ((long)(wz * 4 + kk) * 64 + lane) * 8;
      zresH[kk] = ldfrag(FWZ + o);  pin(zresH[kk]);
      zresL[kk] = ldfrag(FWZl + o); pin(zresL[kk]);
    }
  }
  bf16x8 DH[3][2], DL[3][2];
#pragma unroll
  for (int g = 0; g < 3; ++g)
#pragma unroll
    for (int p = 0; p < 2; ++p) {
      long o = ((long)(g * 16 + 2 * w + p) * 64 + lane) * 8;
      DH[g][p] = ldfrag(FZD + o);  pin(DH[g][p]);
      DL[g][p] = ldfrag(FZDl + o); pin(DL[g][p]);
    }
  bf16x8 RWL[2][8];                       // Whh-lo resident (64 VGPR)
#pragma unroll
  for (int p = 0; p < 2; ++p)
#pragma unroll
    for (int kt = 0; kt < 8; ++kt) {
      long o = ((long)((2 * w + p) * 8 + kt) * 64 + lane) * 8;
      RWL[p][kt] = ldfrag(FWHl + o);
      pin(RWL[p][kt]);
    }

  // ---- hoisted biases -----------------------------------------------------
  int c2 = 16 * w + rowL;                       // hyper col (0..127)
  float bhv = bhy[layer * HH_ + c2];
  float bzv = (w < 6) ? bz[layer * 3 * E_ + c2] : 0.0f;
  float bbv[2];
  bbv[0] = bmain[layer * H_ + 32 * w + rowL];
  bbv[1] = bmain[layer * H_ + 32 * w + 16 + rowL];

  // ---- streamed-weight rotating buffers (slot s holds kt == s mod 3) ------
  bf16x8 bWH[3][2], bYL[3];
#define LOAD_SLOT(S, KT)                                                      \
  {                                                                           \
    long oy = ((long)(w * 12 + (KT)) * 64 + lane) * 8;                        \
    bYL[S] = ldfrag(FHYl + oy);                                               \
    if ((KT) < 8) {                                                           \
      long o0 = ((long)((2 * w) * 8 + (KT)) * 64 + lane) * 8;                 \
      long o1 = ((long)((2 * w + 1) * 8 + (KT)) * 64 + lane) * 8;             \
      bWH[S][0] = ldfrag(FWH + o0);                                           \
      bWH[S][1] = ldfrag(FWH + o1);                                           \
    }                                                                         \
  }
#pragma unroll
  for (int s = 0; s < 3; ++s) LOAD_SLOT(s, s)

  __syncthreads();                        // once; full drain acceptable here

  for (int t = 0; t < T_; ++t) {
    const int pr = t & 1;
    // ---- early per-step input loads (consumed in P2/P6) -------------------
    float xhv[4], xwv[2][4];
#pragma unroll
    for (int r = 0; r < 4; ++r) {
      size_t row = (size_t)(bs + 4 * colG + r) * T_ + t;
      xhv[r] = xH[row * HH_ + c2];
      xwv[0][r] = xW[row * H_ + 32 * w + rowL];
      xwv[1][r] = xW[row * H_ + 32 * w + 16 + rowL];
    }

    // ---- P1: aA (hcat @ HY^T tile w), aW (h @ Whh^T tiles 2w,2w+1) --------
    f32x4 aAe = {}, aAo = {}, aW0 = {}, aW1 = {};
    __builtin_amdgcn_s_setprio(1);
#pragma unroll
    for (int j = 0; j < 12; ++j) {
      const int s = j % 3;
      bf16x8 ah, al;
      if (j < 8) {
        ah = ldfrag(&hc_h[j * 512 + lane * 8]);
        al = ldfrag(&hc_l[j * 512 + lane * 8]);
      } else {
        ah = ldfrag(&hhb_h[pr ^ 1][(j - 8) * 512 + lane * 8]);
        al = ldfrag(&hhb_l[pr ^ 1][(j - 8) * 512 + lane * 8]);
      }
      bf16x8 yh = ldfrag(&hy_lds[(w * 12 + j) * 512 + lane * 8]);
      if (j & 1) aAo = mfma3(ah, al, yh, bYL[s], aAo);
      else       aAe = mfma3(ah, al, yh, bYL[s], aAe);
      if (j < 8) {
        aW0 = mfma3(ah, al, bWH[s][0], RWL[0][j], aW0);
        aW1 = mfma3(ah, al, bWH[s][1], RWL[1][j], aW1);
      }
      if (j < 9) LOAD_SLOT(s, j + 3)      // prefetch kt=j+3 (distance 3)
    }
    __builtin_amdgcn_s_setprio(0);
    f32x4 aA;
#pragma unroll
    for (int r = 0; r < 4; ++r) aA[r] = aAe[r] + aAo[r];

    // refill slots 0..2 for next step (in flight across BA..BC)
#pragma unroll
    for (int s = 0; s < 3; ++s) LOAD_SLOT(s, s)

    // ---- P2: hh_new = tanh(aA + xH + b_hy) -> hhb[pr] (no barrier before) -
    {
      int kfr = w >> 1;
      int hb2 = 2 * (w & 1) + (rowL >> 3);
      int j7 = rowL & 7;
#pragma unroll
      for (int r = 0; r < 4; ++r) {
        float v = tanh_fast(aA[r] + xhv[r] + bhv);
        u16 hi, lo;
        split2(v, hi, lo);
        int di = kfr * 512 + ((4 * colG + r) + 16 * hb2) * 8 + j7;
        hhb_h[pr][di] = hi;
        hhb_l[pr][di] = lo;
      }
    }
    block_sync();                          // BA (hh(t) frags visible)

    // ---- P3/P4: z = hh_new @ Whz^T + bz -> zf frags (waves 0..5) ----------
    if (w < 6) {
      f32x4 aZ = {};
#pragma unroll
      for (int kk = 0; kk < 4; ++kk) {
        bf16x8 ah = ldfrag(&hhb_h[pr][kk * 512 + lane * 8]);
        bf16x8 al = ldfrag(&hhb_l[pr][kk * 512 + lane * 8]);
        aZ = mfma3(ah, al, zresH[kk], zresL[kk], aZ);
      }
      int g = c2 >> 5;                     // c2 = 16w+rowL in [0,96)
      int hb3 = 2 * (w & 1) + (rowL >> 3);
      int j7 = rowL & 7;
#pragma unroll
      for (int r = 0; r < 4; ++r) {
        float v = aZ[r] + bzv;
        u16 hi, lo;
        split2(v, hi, lo);
        int di = g * 512 + ((4 * colG + r) + 16 * hb3) * 8 + j7;
        zf_h[di] = hi;
        zf_l[di] = lo;
      }
    }
    block_sync();                          // BB (zf ready)

    // ---- P5+P6: d_g = z @ Wzd_g^T, accumulate h-arg sequentially over g ---
    float arg[2][4];
#pragma unroll
    for (int p = 0; p < 2; ++p)
#pragma unroll
      for (int r = 0; r < 4; ++r) arg[p][r] = bbv[p];
#pragma unroll
    for (int g = 0; g < 3; ++g) {
      bf16x8 zh = ldfrag(&zf_h[g * 512 + lane * 8]);
      bf16x8 zl = ldfrag(&zf_l[g * 512 + lane * 8]);
#pragma unroll
      for (int p = 0; p < 2; ++p) {
        f32x4 zero = {};
        f32x4 dg = mfma3(zh, zl, DH[g][p], DL[g][p], zero);
#pragma unroll
        for (int r = 0; r < 4; ++r) {
          float mul = (g == 0) ? xwv[p][r]
                    : (g == 1) ? ((p == 0) ? aW0[r] : aW1[r]) : 1.0f;
          arg[p][r] += dg[r] * mul;
        }
      }
    }
#pragma unroll
    for (int p = 0; p < 2; ++p) {
      int c = 32 * w + 16 * p + rowL;
      int hb6 = 2 * p + (rowL >> 3);
      int j7 = rowL & 7;
#pragma unroll
      for (int r = 0; r < 4; ++r) {
        int m = 4 * colG + r;
        float h = tanh_fast(arg[p][r]);
        size_t gi = (size_t)(bs + m) * T_ + t;
        y[gi * H_ + c] = h;
        if (isLast && t == T_ - 1) hlast[(size_t)(bs + m) * H_ + c] = h;
        u16 hi, lo;
        split2(h, hi, lo);
        int di = (c >> 5) * 512 + (m + 16 * hb6) * 8 + j7;
        hc_h[di] = hi;
        hc_l[di] = lo;
      }
    }
    block_sync();                          // BC (h(t) frags ready for P1(t+1))
  }
#undef LOAD_SLOT
}

// ---------------------------------------------------------------------------
extern "C" void kernel_launch(void *const *d_in, const int *in_sizes, int n_in,
                              void *d_out, int out_size, void *d_ws,
                              size_t ws_size, hipStream_t stream) {
  (void)in_sizes; (void)n_in; (void)out_size; (void)ws_size;
  const float *input  = (const float *)d_in[0];
  const float *Wih    = (const float *)d_in[1];
  const float *Whh    = (const float *)d_in[2];
  const float *b      = (const float *)d_in[3];
  const float *Wih_hy = (const float *)d_in[4];
  const float *Whh_hy = (const float *)d_in[5];
  const float *b_hy   = (const float *)d_in[6];
  const float *Whz    = (const float *)d_in[7];
  const float *bz     = (const float *)d_in[8];
  const float *Wzd    = (const float *)d_in[9];

  float *out = (float *)d_out;
  float *xW = (float *)((char *)d_ws + WS_XW);
  float *xH = (float *)((char *)d_ws + WS_XH);
  u16 *fr = (u16 *)((char *)d_ws + WS_FR);
  float *hlast = out + (size_t)BT * H_;

  metarnn_prep<<<dim3(244), dim3(256), 0, stream>>>(Wih, Whh, Wih_hy, Whh_hy,
                                                    Whz, Wzd, fr);
  for (int l = 0; l < 2; ++l) {
    const float *xsrc = (l == 0) ? input : out;   // layer1 reads layer0 output
    const u16 *frl = fr + (size_t)l * LSTRIDE;
    metarnn_gemm<<<dim3(BT / 32), dim3(256), 0, stream>>>(xsrc, frl, xW, xH);
    metarnn_scan<<<dim3(16), dim3(512), 0, stream>>>(
        xW, xH, frl, b, b_hy, bz, out, hlast, l, (l == 1) ? 1 : 0);
  }
}